// Round 1
// baseline (563.359 us; speedup 1.0000x reference)
//
#include <hip/hip_runtime.h>
#include <math.h>

#define BATCH 8192
#define TPB   32      // half-waves: 256 blocks -> 1 wave on each of 256 CUs
#define SLOT  100     // steps per LDS ring slot (record boundary = slot boundary)
#define NSLOT 49      // 49 * 100 = 4900 observed steps
#define RING  3       // slots k, k+1 (in flight), k+2 (being filled)
#define SLOT_BYTES  (SLOT * TPB * 4)   // 12800
#define GROUP_BYTES (10 * TPB * 4)     // 1280

// Round-4 theory: the register double-buffer held only ~6.4 KB in flight per
// wave with a ~500-cycle latency window; measured effective latency ~9000 cyc
// -> 86% waitcnt stall (VALUBusy 13.5%). This version stages dW through an
// LDS ring via global_load_lds dwordx4 DMA: 512 B per instruction (4 rows x
// 128 B), 50 instructions (25 KB) in flight, and a 2-slot (~6000 cyc) latency
// window. Consumer side reads LDS with asm ds_read_b32 groups of 10,
// double-buffered against counted lgkmcnt(10) waits (lgkmcnt is 4-bit: never
// exceed ~20 outstanding). vmcnt retires in order, so slot-level counted
// waits (vmcnt(25)) are exact. Step math is bit-identical to the passing
// kernel.

__device__ __forceinline__ unsigned lds_addr_of(void* p) {
    // generic -> LDS address space; integer value of an as(3) pointer is the
    // 32-bit LDS byte offset (DS ops on gfx9+ ignore m0).
    return (unsigned)(unsigned long long)(__attribute__((address_space(3))) void*)p;
}

#define REP10(M) M(0) M(1) M(2) M(3) M(4) M(5) M(6) M(7) M(8) M(9)

#define DECLA(k) float A##k = 0.0f;
#define DECLB(k) float B##k = 0.0f;

// 10 ds_read_b32 from one base VGPR + compile-time row offsets (row = 128 B).
#define DS_READ10(P, addr) asm volatile( \
    "ds_read_b32 %[d0], %[a] offset:0\n\t" \
    "ds_read_b32 %[d1], %[a] offset:128\n\t" \
    "ds_read_b32 %[d2], %[a] offset:256\n\t" \
    "ds_read_b32 %[d3], %[a] offset:384\n\t" \
    "ds_read_b32 %[d4], %[a] offset:512\n\t" \
    "ds_read_b32 %[d5], %[a] offset:640\n\t" \
    "ds_read_b32 %[d6], %[a] offset:768\n\t" \
    "ds_read_b32 %[d7], %[a] offset:896\n\t" \
    "ds_read_b32 %[d8], %[a] offset:1024\n\t" \
    "ds_read_b32 %[d9], %[a] offset:1152" \
    : [d0] "=v"(P##0), [d1] "=v"(P##1), [d2] "=v"(P##2), [d3] "=v"(P##3), \
      [d4] "=v"(P##4), [d5] "=v"(P##5), [d6] "=v"(P##6), [d7] "=v"(P##7), \
      [d8] "=v"(P##8), [d9] "=v"(P##9) \
    : [a] "v"(addr))

// Wait until only the newest 10 ds_reads (the other group) remain outstanding
// => this group's 10 (older, in-order retire) have landed. "+v" ties make
// every use data-depend on the wait.
#define WAIT10(P) asm volatile("s_waitcnt lgkmcnt(10)" \
    : "+v"(P##0), "+v"(P##1), "+v"(P##2), "+v"(P##3), "+v"(P##4), \
      "+v"(P##5), "+v"(P##6), "+v"(P##7), "+v"(P##8), "+v"(P##9))

#define WAIT10_0(P) asm volatile("s_waitcnt lgkmcnt(0)" \
    : "+v"(P##0), "+v"(P##1), "+v"(P##2), "+v"(P##3), "+v"(P##4), \
      "+v"(P##5), "+v"(P##6), "+v"(P##7), "+v"(P##8), "+v"(P##9))

#define STEP_BODY(dwv) { \
    float dw  = (dwv); \
    float pr  = dtrec * r0; \
    float ps  = pr * s; \
    float r0a = r0 * c1 + c2; \
    float sq  = sqrtf(fabsf(r0)); \
    float g   = dw * volc; \
    s  = s - ps; \
    i_ = i_ * ci + ps; \
    r0 = r0a + sq * g; }

#define STEPA(k) STEP_BODY(A##k)
#define STEPB(k) STEP_BODY(B##k)

// Issue one slot: 25 global_load_lds dwordx4. Each instruction: 32 lanes x
// 16 B = 512 B = 4 consecutive dW rows' 128 B block-slices, landing linearly
// in LDS as ring[slot][4i + (lane>>3)][(lane&7)*4 .. +3]. LDS dest is the
// wave-uniform base; global source is per-lane.
#define ISSUE_SLOT(kk) do { \
    const float* g_ = gp + (size_t)(kk) * (SLOT * BATCH); \
    float* l_ = &ring[(kk) % RING][0][0]; \
    _Pragma("unroll") \
    for (int ii = 0; ii < 25; ++ii) { \
        __builtin_amdgcn_global_load_lds( \
            (__attribute__((address_space(1))) void*)(g_), \
            (__attribute__((address_space(3))) void*)(l_), 16, 0, 0); \
        g_ += 4 * BATCH; \
        l_ += 4 * TPB; \
    } \
} while (0)

__global__ __launch_bounds__(TPB, 1)
void sir_sde_kernel(const float* __restrict__ cond,
                    const float* __restrict__ dW,
                    const float* __restrict__ uu,
                    float* __restrict__ out)
{
    __shared__ float ring[RING][SLOT][TPB];   // 38400 B

    const int t = threadIdx.x;
    const int b = blockIdx.x * TPB + t;
    const int b0 = blockIdx.x * TPB;

    // All compiler-visible loads happen here, BEFORE the DMA pipeline starts,
    // so they are older than every pipelined load (in-order vmcnt retire
    // keeps our counted waits exact).
    const float inf_rate = cond[b * 4 + 0];
    const float rec      = cond[b * 4 + 1];
    const float mr       = cond[b * 4 + 2];
    const float vol      = cond[b * 4 + 3];
    const float u        = uu[b];

    const float dt    = 0.01f;
    const float r0i   = inf_rate / rec;
    const float dtrec = dt * rec;
    const float ci    = 1.0f - dtrec;       // i' = i*ci + ps
    const float c1    = 1.0f - dt * mr;     // r0' = r0*c1 + c2 + sqrt|r0|*g
    const float c2    = (dt * mr) * r0i;
    const float volc  = vol * sqrtf(dt);

    float s  = 0.99f;
    float i_ = 0.01f;
    float r0 = r0i;

    float maxv = -1.0f, maxat = 0.0f;
    float prevlx = 0.0f, sum = 0.0f, sumsq = 0.0f;

    REP10(DECLA)
    REP10(DECLB)

    // Per-lane global source pointer: lane covers row (t>>3), floats
    // b0 + (t&7)*4 .. +3 of each dW row (rows are BATCH floats apart).
    const float* gp = dW + (size_t)(t >> 3) * BATCH + (size_t)(b0 + (t & 7) * 4);

    const unsigned ring_base = lds_addr_of(&ring[0][0][0]) + (unsigned)t * 4u;

    // Pin the scalar loads above the pipeline.
    asm volatile("" ::: "memory");

    // Prologue: slots 0 and 1 in flight (50 outstanding <= 63 vmcnt cap).
    ISSUE_SLOT(0);
    ISSUE_SLOT(1);

#pragma unroll 1
    for (int k = 0; k < NSLOT; ++k) {
        // Outstanding here: slots k, k+1 (25 each; slot k+1 absent at k=48).
        // Wait for slot k (oldest 25) only; k+1 stays in flight.
        if (k + 1 < NSLOT) { asm volatile("s_waitcnt vmcnt(25)"); }
        else               { asm volatile("s_waitcnt vmcnt(0)"); }

        // Refill the slot consumed at iteration k-1 ((k+2)%RING == (k-1)%RING).
        if (k + 2 < NSLOT) ISSUE_SLOT(k + 2);

        unsigned a = ring_base + (unsigned)((k % RING) * SLOT_BYTES);

        // 10 groups of 10 steps, software-pipelined A/B against lgkmcnt(10).
        DS_READ10(A, a); a += GROUP_BYTES;                              // g0
        DS_READ10(B, a); a += GROUP_BYTES; WAIT10(A); REP10(STEPA)      // g1 | c0
        DS_READ10(A, a); a += GROUP_BYTES; WAIT10(B); REP10(STEPB)      // g2 | c1
        DS_READ10(B, a); a += GROUP_BYTES; WAIT10(A); REP10(STEPA)      // g3 | c2
        DS_READ10(A, a); a += GROUP_BYTES; WAIT10(B); REP10(STEPB)      // g4 | c3
        DS_READ10(B, a); a += GROUP_BYTES; WAIT10(A); REP10(STEPA)      // g5 | c4
        DS_READ10(A, a); a += GROUP_BYTES; WAIT10(B); REP10(STEPB)      // g6 | c5
        DS_READ10(B, a); a += GROUP_BYTES; WAIT10(A); REP10(STEPA)      // g7 | c6
        DS_READ10(A, a); a += GROUP_BYTES; WAIT10(B); REP10(STEPB)      // g8 | c7
        DS_READ10(B, a);                   WAIT10(A); REP10(STEPA)      // g9 | c8
                                           WAIT10_0(B); REP10(STEPB)    //    | c9

        // Slot boundary == step 99 (mod 100): record sample k.
        {
            float x = __builtin_isfinite(i_) ? i_ : 0.0f;
            x = fmaxf(x, 1e-5f);
            float lx = logf(x);
            if (k > 0) {
                float d = lx - prevlx;
                sum   += d;
                sumsq += d * d;
            }
            prevlx = lx;
            if (x > maxv) { maxv = x; maxat = (float)k; }  // strict >: first max
        }
    }

    // Everything is drained by construction; belt-and-suspenders.
    asm volatile("s_waitcnt vmcnt(0) lgkmcnt(0)" ::: "memory");

    // Epilogue: std (ddof=0 over 48 diffs), max_at = (argmax + u)/49
    float mean = sum / 48.0f;
    float var  = sumsq / 48.0f - mean * mean;
    var = fmaxf(var, 0.0f);
    float volout    = sqrtf(var);
    float maxat_out = (maxat + u) / 49.0f;

    out[b * 3 + 0] = maxv;
    out[b * 3 + 1] = maxat_out;
    out[b * 3 + 2] = volout;
}

extern "C" void kernel_launch(void* const* d_in, const int* in_sizes, int n_in,
                              void* d_out, int out_size, void* d_ws, size_t ws_size,
                              hipStream_t stream)
{
    (void)in_sizes; (void)n_in; (void)out_size; (void)d_ws; (void)ws_size;
    const float* cond = (const float*)d_in[0];
    const float* dW   = (const float*)d_in[1];
    const float* uu   = (const float*)d_in[2];
    float* out = (float*)d_out;

    dim3 grid(BATCH / TPB), block(TPB);
    hipLaunchKernelGGL(sir_sde_kernel, grid, block, 0, stream, cond, dW, uu, out);
}

// Round 7
// 521.677 us; speedup vs baseline: 1.0799x; 1.0799x over previous
//
#include <hip/hip_runtime.h>
#include <math.h>

#define BATCH 8192
#define TPB   64      // one full wave per block
#define COLS  8       // batch columns per wave
#define NBLK  (BATCH / COLS)        // 1024 blocks -> 4x the waves of v0
#define CHUNK_BYTES 262144u         // 8 steps * BATCH * 4 B

// Round-7: abandon cross-wave producer/consumer (4 identical failures,
// mechanism undiagnosable from source). Same HW goal -- more waves pulling
// independent line streams -- via ONLY v0-validated primitives. Evidence:
// v0 (128-B reqs) and v1 (512-B reqs) both pin at ~0.67 B/cy/wave with equal
// bytes/wave => per-wave intake cap, independent of request size and depth.
// m13's 6.3 TB/s at high occupancy = 0.6-1.3 B/cy/wave share => more waves
// is the only lever. Design: 1024 blocks x 1 wave; each wave owns 8 columns;
// lane l covers step-sub (l>>3), col (l&7), so one 64-lane global_load_dword
// fetches 8 steps x 8 cols = 256 B. All 8 octets run the recurrence
// duplicated, consuming dw via __shfl(R, 8j+c) (same-wave, standard).
// 8 chunks in flight via v0's asm ring: named regs, counted vmcnt(7),
// never vmcnt(0) in steady state. No LDS, no barriers, no cross-wave state.

#define STEP_BODY(dwv) { \
    float dw  = (dwv); \
    float pr  = dtrec * r0; \
    float ps  = pr * s; \
    float r0a = r0 * c1 + c2; \
    float sq  = sqrtf(fabsf(r0)); \
    float g   = dw * volc; \
    s  = s - ps; \
    i_ = i_ * ci + ps; \
    r0 = r0a + sq * g; }

// Issue chunk (cc) into register Rr. saddr = dW (SGPR pair), voffset =
// lane_off + cc*256KB (max 623*256K = 156 MB < 2^32). Volatile asm blocks
// keep program order among themselves; "=v" makes the reg opaque to
// live-range shrinking (the round-0 lesson).
#define ISSUE(Rr, cc) asm volatile( \
    "global_load_dword %[d], %[o], %[sb]" \
    : [d] "=v"(Rr) \
    : [o] "v"(lane_off + (unsigned)(cc) * CHUNK_BYTES), [sb] "s"(dW))

// Wait until only the 7 newer chunk-loads remain outstanding => Rr's chunk
// (the oldest of 8, in-order retire) has landed. "+v" ties every use.
#define WAIT7(Rr) asm volatile("s_waitcnt vmcnt(7)" : "+v"(Rr))

#define RECORD(xx) { \
    float x = __builtin_isfinite(xx) ? (xx) : 0.0f; \
    x = fmaxf(x, 1e-5f); \
    float lx = logf(x); \
    if (reccount > 0) { float d = lx - prevlx; sum += d; sumsq += d * d; } \
    prevlx = lx; \
    if (x > maxv) { maxv = x; maxat = (float)reccount; } \
    ++reccount; }

// Consume the 8 steps of chunk (cidx) held in Rr. Step j's dw for col c is
// in lane 8j + c. Records: global step = 8*cidx + j; at most one per chunk;
// capture i_ at the hit step with a per-step select, record once after.
#define CONSUME(Rr, cidx) do { \
    WAIT7(Rr); \
    const int hit = next_rec - ((cidx) << 3); \
    float x_rec = 0.0f; \
    _Pragma("unroll") \
    for (int j = 0; j < 8; ++j) { \
        float dwv = __shfl(Rr, (j << 3) + c, 64); \
        STEP_BODY(dwv) \
        if (j == hit) x_rec = i_; \
    } \
    if (hit >= 0 && hit < 8) { RECORD(x_rec); next_rec += 100; } \
} while (0)

__global__ __launch_bounds__(TPB, 1)
void sir_sde_kernel(const float* __restrict__ cond,
                    const float* __restrict__ dW,
                    const float* __restrict__ uu,
                    float* __restrict__ out)
{
    const int l = threadIdx.x;          // 0..63
    const int c = l & 7;                // column within the wave's 8
    const int b = blockIdx.x * COLS + c;

    // All compiler-visible vector loads happen before the pipeline; the
    // memory-clobber drain below pins them (loads cannot cross it), so the
    // asm vmcnt counting is exact afterwards.
    const float inf_rate = cond[b * 4 + 0];
    const float rec      = cond[b * 4 + 1];
    const float mr       = cond[b * 4 + 2];
    const float vol      = cond[b * 4 + 3];
    const float u        = uu[b];

    const float dt    = 0.01f;
    const float r0i   = inf_rate / rec;
    const float dtrec = dt * rec;
    const float ci    = 1.0f - dtrec;       // i' = i*ci + ps
    const float c1    = 1.0f - dt * mr;     // r0' = r0*c1 + c2 + sqrt|r0|*g
    const float c2    = (dt * mr) * r0i;
    const float volc  = vol * sqrtf(dt);

    float s  = 0.99f;
    float i_ = 0.01f;
    float r0 = r0i;

    float maxv = -1.0f, maxat = 0.0f;
    float prevlx = 0.0f, sum = 0.0f, sumsq = 0.0f;
    int   reccount = 0;
    int   next_rec = 99;

    // Per-lane byte offset of chunk 0: row (l>>3), col blockIdx.x*8 + (l&7).
    const unsigned lane_off =
        ((unsigned)(l >> 3) * (unsigned)BATCH
         + (unsigned)blockIdx.x * (unsigned)COLS + (unsigned)c) * 4u;

    float R0 = 0.0f, R1 = 0.0f, R2 = 0.0f, R3 = 0.0f;
    float R4 = 0.0f, R5 = 0.0f, R6 = 0.0f, R7 = 0.0f;

    // Drain scalar-phase loads so only pipeline loads count in vmcnt.
    asm volatile("s_waitcnt vmcnt(0)" ::: "memory");

    // Prologue: chunks 0..7 in flight.
    ISSUE(R0, 0); ISSUE(R1, 1); ISSUE(R2, 2); ISSUE(R3, 3);
    ISSUE(R4, 4); ISSUE(R5, 5); ISSUE(R6, 6); ISSUE(R7, 7);

    // 77 iters x 8 chunks x 8 steps = 4928 steps (records end at 4899;
    // trailing steps only touch s/i_/r0). Max chunk issued = 608+15 = 623
    // -> rows <= 4991 < 5000 (dW has NUM_STEPS=5000 rows): always in bounds.
#pragma unroll 1
    for (int it = 0; it < 77; ++it) {
        const int cb = it << 3;
        CONSUME(R0, cb + 0); ISSUE(R0, cb + 8);
        CONSUME(R1, cb + 1); ISSUE(R1, cb + 9);
        CONSUME(R2, cb + 2); ISSUE(R2, cb + 10);
        CONSUME(R3, cb + 3); ISSUE(R3, cb + 11);
        CONSUME(R4, cb + 4); ISSUE(R4, cb + 12);
        CONSUME(R5, cb + 5); ISSUE(R5, cb + 13);
        CONSUME(R6, cb + 6); ISSUE(R6, cb + 14);
        CONSUME(R7, cb + 7); ISSUE(R7, cb + 15);
    }

    // Drain the dangling prefetches before touching memory/exit.
    asm volatile("s_waitcnt vmcnt(0)" ::: "memory");

    // Epilogue: std (ddof=0 over 48 diffs), max_at = (argmax + u)/49.
    float mean = sum / 48.0f;
    float var  = sumsq / 48.0f - mean * mean;
    var = fmaxf(var, 0.0f);
    float volout    = sqrtf(var);
    float maxat_out = (maxat + u) / 49.0f;

    // Octets 1..7 hold identical state; octet 0 writes.
    if (l < 8) {
        out[b * 3 + 0] = maxv;
        out[b * 3 + 1] = maxat_out;
        out[b * 3 + 2] = volout;
    }
}

extern "C" void kernel_launch(void* const* d_in, const int* in_sizes, int n_in,
                              void* d_out, int out_size, void* d_ws, size_t ws_size,
                              hipStream_t stream)
{
    (void)in_sizes; (void)n_in; (void)out_size; (void)d_ws; (void)ws_size;
    const float* cond = (const float*)d_in[0];
    const float* dW   = (const float*)d_in[1];
    const float* uu   = (const float*)d_in[2];
    float* out = (float*)d_out;

    dim3 grid(NBLK), block(TPB);
    hipLaunchKernelGGL(sir_sde_kernel, grid, block, 0, stream, cond, dW, uu, out);
}